// Round 1
// baseline (1875.449 us; speedup 1.0000x reference)
//
#include <hip/hip_runtime.h>

#define NN 6144
#define NF 512
#define NH 256
#define AD 128
#define NC 8

__device__ __forceinline__ float4 ld4(const float* p) {
    return *reinterpret_cast<const float4*>(p);
}
__device__ __forceinline__ void st4(float* p, float4 v) {
    *reinterpret_cast<float4*>(p) = v;
}

// ---------------------------------------------------------------------------
// K0: U_i = Wa_i @ Wagg[i*128:(i+1)*128, :]  ([N,3] each), c = sum_i ba_i@Wagg_i + bagg
// ---------------------------------------------------------------------------
__global__ __launch_bounds__(256) void k0_prep(
    const float* __restrict__ Wa1, const float* __restrict__ Wa2, const float* __restrict__ Wa3,
    const float* __restrict__ ba1, const float* __restrict__ ba2, const float* __restrict__ ba3,
    const float* __restrict__ Wagg, const float* __restrict__ bagg,
    float* __restrict__ U, float* __restrict__ cvec)
{
    int idx = blockIdx.x * 256 + threadIdx.x;
    if (idx < 3 * NN * 3) {
        int i = idx / (NN * 3);
        int rem = idx - i * (NN * 3);
        int r = rem / 3, j = rem - 3 * (rem / 3);
        const float* Wa = (i == 0) ? Wa1 : ((i == 1) ? Wa2 : Wa3);
        float s = 0.f;
        #pragma unroll 4
        for (int k = 0; k < AD; ++k)
            s += Wa[(size_t)r * AD + k] * Wagg[(i * AD + k) * 3 + j];
        U[idx] = s;
    }
    if (blockIdx.x == 0 && threadIdx.x < 3) {
        int j = threadIdx.x;
        float s = bagg[j];
        const float* bas[3] = {ba1, ba2, ba3};
        for (int i = 0; i < 3; ++i)
            for (int k = 0; k < AD; ++k)
                s += bas[i][k] * Wagg[(i * AD + k) * 3 + j];
        cvec[j] = s;
    }
}

// ---------------------------------------------------------------------------
// K1: z4[r,:] = sum_c sum_i adj_i[r,c]*U_i[c,:] + c ; nz = softmax(z4)
// 4 rows per block. Writes nzT[3][N] (for vectorized column access) and output 2.
// ---------------------------------------------------------------------------
__global__ __launch_bounds__(256) void k1_nz(
    const float* __restrict__ adj0, const float* __restrict__ adj1, const float* __restrict__ adj2,
    const float* __restrict__ U, const float* __restrict__ cvec,
    float* __restrict__ nzT, float* __restrict__ out_nz)
{
    int r0 = blockIdx.x * 4;
    int tid = threadIdx.x;
    float acc[4][3] = {};
    for (int c = tid; c < NN; c += 256) {
        float u[3][3];
        #pragma unroll
        for (int i = 0; i < 3; ++i) {
            u[i][0] = U[((size_t)i * NN + c) * 3 + 0];
            u[i][1] = U[((size_t)i * NN + c) * 3 + 1];
            u[i][2] = U[((size_t)i * NN + c) * 3 + 2];
        }
        #pragma unroll
        for (int rr = 0; rr < 4; ++rr) {
            size_t off = (size_t)(r0 + rr) * NN + c;
            float a0 = adj0[off], a1 = adj1[off], a2 = adj2[off];
            acc[rr][0] += a0 * u[0][0] + a1 * u[1][0] + a2 * u[2][0];
            acc[rr][1] += a0 * u[0][1] + a1 * u[1][1] + a2 * u[2][1];
            acc[rr][2] += a0 * u[0][2] + a1 * u[1][2] + a2 * u[2][2];
        }
    }
    __shared__ float red[256][12];
    #pragma unroll
    for (int rr = 0; rr < 4; ++rr)
        #pragma unroll
        for (int j = 0; j < 3; ++j)
            red[tid][rr * 3 + j] = acc[rr][j];
    __syncthreads();
    for (int s = 128; s > 0; s >>= 1) {
        if (tid < s) {
            #pragma unroll
            for (int q = 0; q < 12; ++q) red[tid][q] += red[tid + s][q];
        }
        __syncthreads();
    }
    if (tid < 4) {
        int r = r0 + tid;
        float z0 = red[0][tid * 3 + 0] + cvec[0];
        float z1 = red[0][tid * 3 + 1] + cvec[1];
        float z2 = red[0][tid * 3 + 2] + cvec[2];
        float m = fmaxf(z0, fmaxf(z1, z2));
        float e0 = __expf(z0 - m), e1 = __expf(z1 - m), e2 = __expf(z2 - m);
        float inv = 1.f / (e0 + e1 + e2);
        e0 *= inv; e1 *= inv; e2 *= inv;
        nzT[0 * NN + r] = e0; nzT[1 * NN + r] = e1; nzT[2 * NN + r] = e2;
        out_nz[(size_t)r * 3 + 0] = e0;
        out_nz[(size_t)r * 3 + 1] = e1;
        out_nz[(size_t)r * 3 + 2] = e2;
    }
}

// ---------------------------------------------------------------------------
// K2: adj[r,c] = sum_i nz[c,i] * adj_i[r,c]   (column-scaled, per torch broadcast)
// ---------------------------------------------------------------------------
__global__ __launch_bounds__(256) void k2_adj(
    const float* __restrict__ adj0, const float* __restrict__ adj1, const float* __restrict__ adj2,
    const float* __restrict__ nzT, float* __restrict__ adj)
{
    size_t idx = (size_t)blockIdx.x * 256 + threadIdx.x;
    size_t e = idx * 4;
    int c = (int)(e % NN);
    float4 a0 = ld4(adj0 + e), a1 = ld4(adj1 + e), a2 = ld4(adj2 + e);
    float4 w0 = ld4(nzT + c), w1 = ld4(nzT + NN + c), w2 = ld4(nzT + 2 * NN + c);
    float4 o;
    o.x = w0.x * a0.x + w1.x * a1.x + w2.x * a2.x;
    o.y = w0.y * a0.y + w1.y * a1.y + w2.y * a2.y;
    o.z = w0.z * a0.z + w1.z * a1.z + w2.z * a2.z;
    o.w = w0.w * a0.w + w1.w * a1.w + w2.w * a2.w;
    st4(adj + e, o);
}

// ---------------------------------------------------------------------------
// Generic tiled fp32 GEMM: C[M,Ncols] = A[M,K](lda) @ B[K,Ncols](ldb) (+bias)(relu)
// 64x64 tile, BK=32, 256 threads, 4x4 micro-tile.
// ---------------------------------------------------------------------------
#define BM 64
#define BN 64
#define BK 32
#define ASTR 68   // padded stride for transposed A tile (keeps b128 16B-aligned)

__global__ __launch_bounds__(256) void gemm64(
    const float* __restrict__ A, int lda,
    const float* __restrict__ B, int ldb,
    float* __restrict__ C, int ldc,
    int Kdim, const float* __restrict__ bias, int relu)
{
    __shared__ float As[BK * ASTR];
    __shared__ float Bs[BK * BN];
    int tid = threadIdx.x;
    int tm = tid >> 4, tn = tid & 15;
    int rowBase = blockIdx.y * BM, colBase = blockIdx.x * BN;
    float acc[4][4] = {};
    for (int k0 = 0; k0 < Kdim; k0 += BK) {
        #pragma unroll
        for (int it = 0; it < 2; ++it) {
            int lin = it * 256 + tid;
            int am = lin >> 3, ak4 = lin & 7;
            float4 a = ld4(A + (size_t)(rowBase + am) * lda + k0 + ak4 * 4);
            int kk = ak4 * 4;
            As[(kk + 0) * ASTR + am] = a.x;
            As[(kk + 1) * ASTR + am] = a.y;
            As[(kk + 2) * ASTR + am] = a.z;
            As[(kk + 3) * ASTR + am] = a.w;
        }
        #pragma unroll
        for (int it = 0; it < 2; ++it) {
            int lin = it * 256 + tid;
            int bk = lin >> 4, bn4 = lin & 15;
            float4 b = ld4(B + (size_t)(k0 + bk) * ldb + colBase + bn4 * 4);
            st4(&Bs[bk * BN + bn4 * 4], b);
        }
        __syncthreads();
        #pragma unroll
        for (int k = 0; k < BK; ++k) {
            float4 av = *reinterpret_cast<const float4*>(&As[k * ASTR + tm * 4]);
            float4 bv = *reinterpret_cast<const float4*>(&Bs[k * BN + tn * 4]);
            float am_[4] = {av.x, av.y, av.z, av.w};
            float bn_[4] = {bv.x, bv.y, bv.z, bv.w};
            #pragma unroll
            for (int i = 0; i < 4; ++i)
                #pragma unroll
                for (int j = 0; j < 4; ++j)
                    acc[i][j] += am_[i] * bn_[j];
        }
        __syncthreads();
    }
    #pragma unroll
    for (int i = 0; i < 4; ++i) {
        int row = rowBase + tm * 4 + i;
        int col = colBase + tn * 4;
        float4 o = {acc[i][0], acc[i][1], acc[i][2], acc[i][3]};
        if (bias) {
            o.x += bias[col]; o.y += bias[col + 1];
            o.z += bias[col + 2]; o.w += bias[col + 3];
        }
        if (relu) {
            o.x = fmaxf(o.x, 0.f); o.y = fmaxf(o.y, 0.f);
            o.z = fmaxf(o.z, 0.f); o.w = fmaxf(o.w, 0.f);
        }
        st4(C + (size_t)row * ldc + col, o);
    }
}

// ---------------------------------------------------------------------------
// K6a: S = adj * (Q @ K^T), in-place on the adj buffer. Both operands row-major
// [*,256]; B tile loaded like A (transpose-store).
// ---------------------------------------------------------------------------
__global__ __launch_bounds__(256) void qkt_mask(
    const float* __restrict__ Q, const float* __restrict__ Km, float* __restrict__ S)
{
    __shared__ float As[BK * ASTR];
    __shared__ float Bs[BK * ASTR];
    int tid = threadIdx.x;
    int tm = tid >> 4, tn = tid & 15;
    int rowBase = blockIdx.y * BM, colBase = blockIdx.x * BN;
    float acc[4][4] = {};
    for (int k0 = 0; k0 < NH; k0 += BK) {
        #pragma unroll
        for (int it = 0; it < 2; ++it) {
            int lin = it * 256 + tid;
            int am = lin >> 3, ak4 = lin & 7;
            int kk = ak4 * 4;
            float4 a = ld4(Q + (size_t)(rowBase + am) * NH + k0 + ak4 * 4);
            As[(kk + 0) * ASTR + am] = a.x;
            As[(kk + 1) * ASTR + am] = a.y;
            As[(kk + 2) * ASTR + am] = a.z;
            As[(kk + 3) * ASTR + am] = a.w;
            float4 b = ld4(Km + (size_t)(colBase + am) * NH + k0 + ak4 * 4);
            Bs[(kk + 0) * ASTR + am] = b.x;
            Bs[(kk + 1) * ASTR + am] = b.y;
            Bs[(kk + 2) * ASTR + am] = b.z;
            Bs[(kk + 3) * ASTR + am] = b.w;
        }
        __syncthreads();
        #pragma unroll
        for (int k = 0; k < BK; ++k) {
            float4 av = *reinterpret_cast<const float4*>(&As[k * ASTR + tm * 4]);
            float4 bv = *reinterpret_cast<const float4*>(&Bs[k * ASTR + tn * 4]);
            float am_[4] = {av.x, av.y, av.z, av.w};
            float bn_[4] = {bv.x, bv.y, bv.z, bv.w};
            #pragma unroll
            for (int i = 0; i < 4; ++i)
                #pragma unroll
                for (int j = 0; j < 4; ++j)
                    acc[i][j] += am_[i] * bn_[j];
        }
        __syncthreads();
    }
    #pragma unroll
    for (int i = 0; i < 4; ++i) {
        size_t off = (size_t)(rowBase + tm * 4 + i) * NN + colBase + tn * 4;
        float4 m = ld4(S + off);
        float4 o = {m.x * acc[i][0], m.y * acc[i][1], m.z * acc[i][2], m.w * acc[i][3]};
        st4(S + off, o);
    }
}

// ---------------------------------------------------------------------------
// K6b: in-place row softmax over N=6144 columns. One block per row,
// 24 elements per thread kept in registers.
// ---------------------------------------------------------------------------
__global__ __launch_bounds__(256) void k6b_softmax(float* __restrict__ S)
{
    int r = blockIdx.x, tid = threadIdx.x;
    float* row = S + (size_t)r * NN;
    float v[24];
    #pragma unroll
    for (int i = 0; i < 24; ++i) v[i] = row[tid + i * 256];
    float m = v[0];
    #pragma unroll
    for (int i = 1; i < 24; ++i) m = fmaxf(m, v[i]);
    #pragma unroll
    for (int o = 32; o > 0; o >>= 1) m = fmaxf(m, __shfl_xor(m, o));
    __shared__ float redm[4];
    __shared__ float reds[4];
    if ((tid & 63) == 0) redm[tid >> 6] = m;
    __syncthreads();
    m = fmaxf(fmaxf(redm[0], redm[1]), fmaxf(redm[2], redm[3]));
    float s = 0.f;
    #pragma unroll
    for (int i = 0; i < 24; ++i) { v[i] = __expf(v[i] - m); s += v[i]; }
    #pragma unroll
    for (int o = 32; o > 0; o >>= 1) s += __shfl_xor(s, o);
    if ((tid & 63) == 0) reds[tid >> 6] = s;
    __syncthreads();
    s = reds[0] + reds[1] + reds[2] + reds[3];
    float inv = 1.f / s;
    #pragma unroll
    for (int i = 0; i < 24; ++i) row[tid + i * 256] = v[i] * inv;
}

// ---------------------------------------------------------------------------
// K6d: Y = Xt @ W2   ([N,256]@[256,8])
// ---------------------------------------------------------------------------
__global__ __launch_bounds__(256) void k6d_Y(
    const float* __restrict__ Xt, const float* __restrict__ W2, float* __restrict__ Y)
{
    int idx = blockIdx.x * 256 + threadIdx.x;
    int r = idx >> 3, j = idx & 7;
    float s = 0.f;
    #pragma unroll 4
    for (int k = 0; k < NH; ++k) s += Xt[(size_t)r * NH + k] * W2[k * 8 + j];
    Y[idx] = s;
}

// ---------------------------------------------------------------------------
// K7: z[r,:] = sum_c adj[r,c]*Y[c,:] + b2 ; out = softmax(z).
// adj recomputed on the fly from adj0..2 and nzT (avoids a 2nd NxN buffer).
// ---------------------------------------------------------------------------
__global__ __launch_bounds__(256) void k7_out(
    const float* __restrict__ adj0, const float* __restrict__ adj1, const float* __restrict__ adj2,
    const float* __restrict__ nzT, const float* __restrict__ Y,
    const float* __restrict__ b2, float* __restrict__ out)
{
    int r = blockIdx.x, tid = threadIdx.x;
    float acc[8] = {};
    size_t rowOff = (size_t)r * NN;
    for (int c = tid; c < NN; c += 256) {
        float w0 = nzT[c], w1 = nzT[NN + c], w2 = nzT[2 * NN + c];
        float a = w0 * adj0[rowOff + c] + w1 * adj1[rowOff + c] + w2 * adj2[rowOff + c];
        const float* y = Y + (size_t)c * 8;
        float4 y0 = ld4(y), y1 = ld4(y + 4);
        acc[0] += a * y0.x; acc[1] += a * y0.y; acc[2] += a * y0.z; acc[3] += a * y0.w;
        acc[4] += a * y1.x; acc[5] += a * y1.y; acc[6] += a * y1.z; acc[7] += a * y1.w;
    }
    __shared__ float red[256][9];
    #pragma unroll
    for (int j = 0; j < 8; ++j) red[tid][j] = acc[j];
    __syncthreads();
    for (int s2 = 128; s2 > 0; s2 >>= 1) {
        if (tid < s2) {
            #pragma unroll
            for (int j = 0; j < 8; ++j) red[tid][j] += red[tid + s2][j];
        }
        __syncthreads();
    }
    if (tid == 0) {
        float z[8];
        float m = -1e30f;
        #pragma unroll
        for (int j = 0; j < 8; ++j) { z[j] = red[0][j] + b2[j]; m = fmaxf(m, z[j]); }
        float s = 0.f;
        #pragma unroll
        for (int j = 0; j < 8; ++j) { z[j] = __expf(z[j] - m); s += z[j]; }
        float inv = 1.f / s;
        #pragma unroll
        for (int j = 0; j < 8; ++j) out[(size_t)r * NC + j] = z[j] * inv;
    }
}

// ---------------------------------------------------------------------------
extern "C" void kernel_launch(void* const* d_in, const int* in_sizes, int n_in,
                              void* d_out, int out_size, void* d_ws, size_t ws_size,
                              hipStream_t stream)
{
    const float* adj0 = (const float*)d_in[0];
    const float* adj1 = (const float*)d_in[1];
    const float* adj2 = (const float*)d_in[2];
    const float* feat = (const float*)d_in[3];
    const float* Wa1 = (const float*)d_in[4];
    const float* ba1 = (const float*)d_in[5];
    const float* Wa2 = (const float*)d_in[6];
    const float* ba2 = (const float*)d_in[7];
    const float* Wa3 = (const float*)d_in[8];
    const float* ba3 = (const float*)d_in[9];
    const float* Wagg = (const float*)d_in[10];
    const float* bagg = (const float*)d_in[11];
    const float* W1 = (const float*)d_in[12];
    const float* b1 = (const float*)d_in[13];
    const float* Wq = (const float*)d_in[14];
    const float* bq = (const float*)d_in[15];
    const float* Wk = (const float*)d_in[16];
    const float* bk = (const float*)d_in[17];
    const float* Wv = (const float*)d_in[18];
    const float* bv = (const float*)d_in[19];
    const float* W2 = (const float*)d_in[20];
    const float* b2 = (const float*)d_in[21];
    float* out = (float*)d_out;            // [N*8] softmax(z) then [N*3] nz
    float* ws = (float*)d_ws;

    // workspace layout (floats)
    const size_t sz_adj = (size_t)NN * NN;
    float* buf_adj = ws;                       // adj -> A_tilde -> attention (in place)
    float* nzT     = buf_adj + sz_adj;         // [3][N]
    float* U       = nzT + 3 * NN;             // [3][N][3]
    float* cvec    = U + 9 * NN;               // [3] (+1 pad)
    float* fW1     = cvec + 4;                 // [N,256]
    float* x       = fW1 + (size_t)NN * NH;    // [N,256]
    float* Qm      = x + (size_t)NN * NH;      // [N,256]
    float* Km      = Qm + (size_t)NN * NH;     // [N,256]
    float* Vm      = Km + (size_t)NN * NH;     // [N,256]
    float* Xt      = Vm + (size_t)NN * NH;     // [N,256]
    float* Y       = Xt + (size_t)NN * NH;     // [N,8]

    float* out_nz = out + (size_t)NN * NC;

    // K0: U, c
    k0_prep<<<216, 256, 0, stream>>>(Wa1, Wa2, Wa3, ba1, ba2, ba3, Wagg, bagg, U, cvec);
    // K1: nz (+ output 2)
    k1_nz<<<NN / 4, 256, 0, stream>>>(adj0, adj1, adj2, U, cvec, nzT, out_nz);
    // K2: adj
    k2_adj<<<(int)(sz_adj / 4 / 256), 256, 0, stream>>>(adj0, adj1, adj2, nzT, buf_adj);
    // K3: fW1 = features @ W1
    gemm64<<<dim3(NH / BN, NN / BM), 256, 0, stream>>>(feat, NF, W1, NH, fW1, NH, NF, nullptr, 0);
    // K4: x = relu(adj @ fW1 + b1)
    gemm64<<<dim3(NH / BN, NN / BM), 256, 0, stream>>>(buf_adj, NN, fW1, NH, x, NH, NN, b1, 1);
    // K5: Q, K, V
    gemm64<<<dim3(NH / BN, NN / BM), 256, 0, stream>>>(x, NH, Wq, NH, Qm, NH, NH, bq, 0);
    gemm64<<<dim3(NH / BN, NN / BM), 256, 0, stream>>>(x, NH, Wk, NH, Km, NH, NH, bk, 0);
    gemm64<<<dim3(NH / BN, NN / BM), 256, 0, stream>>>(x, NH, Wv, NH, Vm, NH, NH, bv, 0);
    // K6a: S = adj * (Q@K^T) in place
    qkt_mask<<<dim3(NN / BN, NN / BM), 256, 0, stream>>>(Qm, Km, buf_adj);
    // K6b: attention = softmax(S) rows, in place
    k6b_softmax<<<NN, 256, 0, stream>>>(buf_adj);
    // K6c: Xt = relu(attention @ V)   (gcn_norm scale == 1/(1+1e-9), negligible)
    gemm64<<<dim3(NH / BN, NN / BM), 256, 0, stream>>>(buf_adj, NN, Vm, NH, Xt, NH, NN, nullptr, 1);
    // K6d: Y = Xt @ W2
    k6d_Y<<<NN * NC / 256, 256, 0, stream>>>(Xt, W2, Y);
    // K7: out = softmax(adj @ Y + b2), adj recomputed on the fly
    k7_out<<<NN, 256, 0, stream>>>(adj0, adj1, adj2, nzT, Y, b2, out);
}

// Round 2
// 1179.426 us; speedup vs baseline: 1.5901x; 1.5901x over previous
//
#include <hip/hip_runtime.h>

#define NN 6144
#define NF 512
#define NH 256
#define AD 128
#define NC 8

typedef short bf16x8 __attribute__((ext_vector_type(8)));
typedef float f32x4 __attribute__((ext_vector_type(4)));

__device__ __forceinline__ float4 ld4(const float* p) {
    return *reinterpret_cast<const float4*>(p);
}
__device__ __forceinline__ void st4(float* p, float4 v) {
    *reinterpret_cast<float4*>(p) = v;
}

__device__ __forceinline__ f32x4 mfma16(bf16x8 a, bf16x8 b, f32x4 c) {
    return __builtin_amdgcn_mfma_f32_16x16x32_bf16(a, b, c, 0, 0, 0);
}

// async global->LDS, 16B per lane; ldsptr must be wave-uniform (HW: base+lane*16)
__device__ __forceinline__ void async_copy16(const void* g, void* lds) {
    __builtin_amdgcn_global_load_lds(
        (const __attribute__((address_space(1))) void*)g,
        (__attribute__((address_space(3))) void*)lds, 16, 0, 0);
}

// fp32 -> bf16 hi (RNE) + bf16 lo (RNE of residual): ~16-bit mantissa total
__device__ __forceinline__ void split1(float f, ushort& h, ushort& l) {
    unsigned u = __float_as_uint(f);
    unsigned hr = (u + 0x7FFFu + ((u >> 16) & 1u)) >> 16;
    float fh = __uint_as_float(hr << 16);
    float fl = f - fh;
    unsigned ul = __float_as_uint(fl);
    unsigned lr = (ul + 0x7FFFu + ((ul >> 16) & 1u)) >> 16;
    h = (ushort)hr; l = (ushort)lr;
}

// ---------------------------------------------------------------------------
// K0: U_i = Wa_i @ Wagg_slice_i  ([N,3] each), cvec = sum_i ba_i@Wagg_i + bagg
// ---------------------------------------------------------------------------
__global__ __launch_bounds__(256) void k0_prep(
    const float* __restrict__ Wa1, const float* __restrict__ Wa2, const float* __restrict__ Wa3,
    const float* __restrict__ ba1, const float* __restrict__ ba2, const float* __restrict__ ba3,
    const float* __restrict__ Wagg, const float* __restrict__ bagg,
    float* __restrict__ U, float* __restrict__ cvec)
{
    int idx = blockIdx.x * 256 + threadIdx.x;
    if (idx < 3 * NN * 3) {
        int i = idx / (NN * 3);
        int rem = idx - i * (NN * 3);
        int r = rem / 3, j = rem - 3 * (rem / 3);
        const float* Wa = (i == 0) ? Wa1 : ((i == 1) ? Wa2 : Wa3);
        float s = 0.f;
        #pragma unroll 4
        for (int k = 0; k < AD; ++k)
            s += Wa[(size_t)r * AD + k] * Wagg[(i * AD + k) * 3 + j];
        U[idx] = s;
    }
    if (blockIdx.x == 0 && threadIdx.x < 3) {
        int j = threadIdx.x;
        float s = bagg[j];
        const float* bas[3] = {ba1, ba2, ba3};
        for (int i = 0; i < 3; ++i)
            for (int k = 0; k < AD; ++k)
                s += bas[i][k] * Wagg[(i * AD + k) * 3 + j];
        cvec[j] = s;
    }
}

// ---------------------------------------------------------------------------
// K1: z4[r,:] = sum_c sum_i adj_i[r,c]*U_i[c,:] + cvec ; nz = softmax(z4)
// ---------------------------------------------------------------------------
__global__ __launch_bounds__(256) void k1_nz(
    const float* __restrict__ adj0, const float* __restrict__ adj1, const float* __restrict__ adj2,
    const float* __restrict__ U, const float* __restrict__ cvec,
    float* __restrict__ nzT, float* __restrict__ out_nz)
{
    int r0 = blockIdx.x * 4;
    int tid = threadIdx.x;
    float acc[4][3] = {};
    for (int c = tid; c < NN; c += 256) {
        float u[3][3];
        #pragma unroll
        for (int i = 0; i < 3; ++i) {
            u[i][0] = U[((size_t)i * NN + c) * 3 + 0];
            u[i][1] = U[((size_t)i * NN + c) * 3 + 1];
            u[i][2] = U[((size_t)i * NN + c) * 3 + 2];
        }
        #pragma unroll
        for (int rr = 0; rr < 4; ++rr) {
            size_t off = (size_t)(r0 + rr) * NN + c;
            float a0 = adj0[off], a1 = adj1[off], a2 = adj2[off];
            acc[rr][0] += a0 * u[0][0] + a1 * u[1][0] + a2 * u[2][0];
            acc[rr][1] += a0 * u[0][1] + a1 * u[1][1] + a2 * u[2][1];
            acc[rr][2] += a0 * u[0][2] + a1 * u[1][2] + a2 * u[2][2];
        }
    }
    __shared__ float red[256][12];
    #pragma unroll
    for (int rr = 0; rr < 4; ++rr)
        #pragma unroll
        for (int j = 0; j < 3; ++j)
            red[tid][rr * 3 + j] = acc[rr][j];
    __syncthreads();
    for (int s = 128; s > 0; s >>= 1) {
        if (tid < s) {
            #pragma unroll
            for (int q = 0; q < 12; ++q) red[tid][q] += red[tid + s][q];
        }
        __syncthreads();
    }
    if (tid < 4) {
        int r = r0 + tid;
        float z0 = red[0][tid * 3 + 0] + cvec[0];
        float z1 = red[0][tid * 3 + 1] + cvec[1];
        float z2 = red[0][tid * 3 + 2] + cvec[2];
        float m = fmaxf(z0, fmaxf(z1, z2));
        float e0 = __expf(z0 - m), e1 = __expf(z1 - m), e2 = __expf(z2 - m);
        float inv = 1.f / (e0 + e1 + e2);
        e0 *= inv; e1 *= inv; e2 *= inv;
        nzT[0 * NN + r] = e0; nzT[1 * NN + r] = e1; nzT[2 * NN + r] = e2;
        out_nz[(size_t)r * 3 + 0] = e0;
        out_nz[(size_t)r * 3 + 1] = e1;
        out_nz[(size_t)r * 3 + 2] = e2;
    }
}

// ---------------------------------------------------------------------------
// K2: adj[r,c] = sum_i nz[c,i] * adj_i[r,c]
// ---------------------------------------------------------------------------
__global__ __launch_bounds__(256) void k2_adj(
    const float* __restrict__ adj0, const float* __restrict__ adj1, const float* __restrict__ adj2,
    const float* __restrict__ nzT, float* __restrict__ adj)
{
    size_t idx = (size_t)blockIdx.x * 256 + threadIdx.x;
    size_t e = idx * 4;
    int c = (int)(e % NN);
    float4 a0 = ld4(adj0 + e), a1 = ld4(adj1 + e), a2 = ld4(adj2 + e);
    float4 w0 = ld4(nzT + c), w1 = ld4(nzT + NN + c), w2 = ld4(nzT + 2 * NN + c);
    float4 o;
    o.x = w0.x * a0.x + w1.x * a1.x + w2.x * a2.x;
    o.y = w0.y * a0.y + w1.y * a1.y + w2.y * a2.y;
    o.z = w0.z * a0.z + w1.z * a1.z + w2.z * a2.z;
    o.w = w0.w * a0.w + w1.w * a1.w + w2.w * a2.w;
    st4(adj + e, o);
}

// ---------------------------------------------------------------------------
// fp32 tiled GEMM (kept for the small K3/K5 GEMMs)
// ---------------------------------------------------------------------------
#define BM 64
#define BN 64
#define BK 32
#define ASTR 68

__global__ __launch_bounds__(256) void gemm64(
    const float* __restrict__ A, int lda,
    const float* __restrict__ B, int ldb,
    float* __restrict__ C, int ldc,
    int Kdim, const float* __restrict__ bias, int relu)
{
    __shared__ float As[BK * ASTR];
    __shared__ float Bs[BK * BN];
    int tid = threadIdx.x;
    int tm = tid >> 4, tn = tid & 15;
    int rowBase = blockIdx.y * BM, colBase = blockIdx.x * BN;
    float acc[4][4] = {};
    for (int k0 = 0; k0 < Kdim; k0 += BK) {
        #pragma unroll
        for (int it = 0; it < 2; ++it) {
            int lin = it * 256 + tid;
            int am = lin >> 3, ak4 = lin & 7;
            float4 a = ld4(A + (size_t)(rowBase + am) * lda + k0 + ak4 * 4);
            int kk = ak4 * 4;
            As[(kk + 0) * ASTR + am] = a.x;
            As[(kk + 1) * ASTR + am] = a.y;
            As[(kk + 2) * ASTR + am] = a.z;
            As[(kk + 3) * ASTR + am] = a.w;
        }
        #pragma unroll
        for (int it = 0; it < 2; ++it) {
            int lin = it * 256 + tid;
            int bk = lin >> 4, bn4 = lin & 15;
            float4 b = ld4(B + (size_t)(k0 + bk) * ldb + colBase + bn4 * 4);
            st4(&Bs[bk * BN + bn4 * 4], b);
        }
        __syncthreads();
        #pragma unroll
        for (int k = 0; k < BK; ++k) {
            float4 av = *reinterpret_cast<const float4*>(&As[k * ASTR + tm * 4]);
            float4 bv = *reinterpret_cast<const float4*>(&Bs[k * BN + tn * 4]);
            float am_[4] = {av.x, av.y, av.z, av.w};
            float bn_[4] = {bv.x, bv.y, bv.z, bv.w};
            #pragma unroll
            for (int i = 0; i < 4; ++i)
                #pragma unroll
                for (int j = 0; j < 4; ++j)
                    acc[i][j] += am_[i] * bn_[j];
        }
        __syncthreads();
    }
    #pragma unroll
    for (int i = 0; i < 4; ++i) {
        int row = rowBase + tm * 4 + i;
        int col = colBase + tn * 4;
        float4 o = {acc[i][0], acc[i][1], acc[i][2], acc[i][3]};
        if (bias) {
            o.x += bias[col]; o.y += bias[col + 1];
            o.z += bias[col + 2]; o.w += bias[col + 3];
        }
        if (relu) {
            o.x = fmaxf(o.x, 0.f); o.y = fmaxf(o.y, 0.f);
            o.z = fmaxf(o.z, 0.f); o.w = fmaxf(o.w, 0.f);
        }
        st4(C + (size_t)row * ldc + col, o);
    }
}

// ---------------------------------------------------------------------------
// cvt_hl: fp32 plane -> separate hi/lo bf16 planes (same layout)
// ---------------------------------------------------------------------------
__global__ __launch_bounds__(256) void cvt_hl(
    const float* __restrict__ in, ushort* __restrict__ hi, ushort* __restrict__ lo)
{
    size_t base = ((size_t)blockIdx.x * 256 + threadIdx.x) * 4;
    float4 v = ld4(in + base);
    ushort4 h, l;
    split1(v.x, h.x, l.x); split1(v.y, h.y, l.y);
    split1(v.z, h.z, l.z); split1(v.w, h.w, l.w);
    *reinterpret_cast<ushort4*>(hi + base) = h;
    *reinterpret_cast<ushort4*>(lo + base) = l;
}

// ---------------------------------------------------------------------------
// cvt_t: [R,C] fp32 -> [C,R] hi/lo bf16 planes (transpose + split)
// ---------------------------------------------------------------------------
__global__ __launch_bounds__(256) void cvt_t(
    const float* __restrict__ in, int R, int C,
    ushort* __restrict__ outhi, ushort* __restrict__ outlo)
{
    __shared__ float t[32][33];
    int rb = blockIdx.x * 32, cb = blockIdx.y * 32;
    int tid = threadIdx.x;
    int lr = tid >> 3, lc4 = (tid & 7) * 4;
    float4 v = ld4(in + (size_t)(rb + lr) * C + cb + lc4);
    t[lr][lc4 + 0] = v.x; t[lr][lc4 + 1] = v.y;
    t[lr][lc4 + 2] = v.z; t[lr][lc4 + 3] = v.w;
    __syncthreads();
    ushort4 h, l;
    split1(t[lc4 + 0][lr], h.x, l.x);
    split1(t[lc4 + 1][lr], h.y, l.y);
    split1(t[lc4 + 2][lr], h.z, l.z);
    split1(t[lc4 + 3][lr], h.w, l.w);
    size_t o = (size_t)(cb + lr) * R + rb + lc4;
    *reinterpret_cast<ushort4*>(outhi + o) = h;
    *reinterpret_cast<ushort4*>(outlo + o) = l;
}

// ---------------------------------------------------------------------------
// gemm_a32_bsplit: Cpart[ks] = A_f32[M,K] @ B (B^T hi/lo bf16 planes [Ncol,K])
// 128x128 tile, split-bf16 (3 MFMA products), split-K=4. A converted in staging.
// ---------------------------------------------------------------------------
#define GBM 128
#define GBN 128
#define GBK 32
#define ASTRS 40   // shorts per A-tile row (32 + 8 pad -> 80B, 2-way-free banks)

__global__ __launch_bounds__(256) void gemm_a32_bsplit(
    const float* __restrict__ A, int lda,
    const ushort* __restrict__ BThi, const ushort* __restrict__ BTlo, int ldbT,
    float* __restrict__ Cpart, int ldc, int Mtotal, int kspan)
{
    int nt = blockIdx.x >> 2;
    int ks = blockIdx.x & 3;
    int rowBase = blockIdx.y * GBM;
    int colBase = nt * GBN;
    int k_begin = ks * kspan;
    int k_end = k_begin + kspan;

    __shared__ ushort Ahi[GBM * ASTRS];
    __shared__ ushort Alo[GBM * ASTRS];
    __shared__ ushort Bhi[GBN * GBK];
    __shared__ ushort Blo[GBN * GBK];

    int tid = threadIdx.x, lane = tid & 63, wave = tid >> 6;
    int wi = wave >> 1, wj = wave & 1;
    int lm = lane & 15, lk = lane >> 4;

    f32x4 acc[4][4] = {};

    for (int k0 = k_begin; k0 < k_end; k0 += GBK) {
        // B: async global->LDS (pre-split bf16 planes), 2 chunks/wave/plane
        #pragma unroll
        for (int p = 0; p < 2; ++p) {
            int ch = wave * 2 + p;
            int brow = ch * 16 + (lane >> 2);
            size_t goff = ((size_t)(colBase + brow) * ldbT + k0) * 2 + (size_t)(lane & 3) * 16;
            async_copy16((const char*)BThi + goff, (char*)Bhi + ch * 1024);
            async_copy16((const char*)BTlo + goff, (char*)Blo + ch * 1024);
        }
        // A: fp32 load -> split -> LDS
        #pragma unroll
        for (int it = 0; it < 4; ++it) {
            int lin = it * 256 + tid;
            int ar = lin >> 3, as = lin & 7;
            float4 v = ld4(A + (size_t)(rowBase + ar) * lda + k0 + as * 4);
            ushort4 h, l;
            split1(v.x, h.x, l.x); split1(v.y, h.y, l.y);
            split1(v.z, h.z, l.z); split1(v.w, h.w, l.w);
            *reinterpret_cast<ushort4*>(&Ahi[ar * ASTRS + as * 4]) = h;
            *reinterpret_cast<ushort4*>(&Alo[ar * ASTRS + as * 4]) = l;
        }
        __syncthreads();
        bf16x8 af[4], al[4], bh[4], bl[4];
        #pragma unroll
        for (int i = 0; i < 4; ++i) {
            int r = wi * 64 + i * 16 + lm;
            af[i] = *reinterpret_cast<const bf16x8*>(&Ahi[r * ASTRS + lk * 8]);
            al[i] = *reinterpret_cast<const bf16x8*>(&Alo[r * ASTRS + lk * 8]);
        }
        #pragma unroll
        for (int j = 0; j < 4; ++j) {
            int n = wj * 64 + j * 16 + lm;
            bh[j] = *reinterpret_cast<const bf16x8*>(&Bhi[n * GBK + lk * 8]);
            bl[j] = *reinterpret_cast<const bf16x8*>(&Blo[n * GBK + lk * 8]);
        }
        #pragma unroll
        for (int i = 0; i < 4; ++i)
            #pragma unroll
            for (int j = 0; j < 4; ++j) {
                acc[i][j] = mfma16(af[i], bh[j], acc[i][j]);
                acc[i][j] = mfma16(af[i], bl[j], acc[i][j]);
                acc[i][j] = mfma16(al[i], bh[j], acc[i][j]);
            }
        __syncthreads();
    }
    float* Cp = Cpart + (size_t)ks * Mtotal * ldc;
    #pragma unroll
    for (int i = 0; i < 4; ++i)
        #pragma unroll
        for (int j = 0; j < 4; ++j) {
            int row0 = rowBase + wi * 64 + i * 16 + lk * 4;
            int col = colBase + wj * 64 + j * 16 + lm;
            #pragma unroll
            for (int r = 0; r < 4; ++r)
                Cp[(size_t)(row0 + r) * ldc + col] = acc[i][j][r];
        }
}

// ---------------------------------------------------------------------------
// reduce4: out = (relu)(sum_ks Cpart[ks] + bias)
// ---------------------------------------------------------------------------
__global__ __launch_bounds__(256) void reduce4(
    const float* __restrict__ Cpart, const float* __restrict__ bias,
    float* __restrict__ out, int relu)
{
    size_t base = ((size_t)blockIdx.x * 256 + threadIdx.x) * 4;
    const size_t stride = (size_t)NN * NH;
    float4 a = ld4(Cpart + base);
    float4 b = ld4(Cpart + stride + base);
    float4 c = ld4(Cpart + 2 * stride + base);
    float4 d = ld4(Cpart + 3 * stride + base);
    float4 o = {a.x + b.x + c.x + d.x, a.y + b.y + c.y + d.y,
                a.z + b.z + c.z + d.z, a.w + b.w + c.w + d.w};
    if (bias) {
        int col = (int)(base & (NH - 1));
        float4 bb = ld4(bias + col);
        o.x += bb.x; o.y += bb.y; o.z += bb.z; o.w += bb.w;
    }
    if (relu) {
        o.x = fmaxf(o.x, 0.f); o.y = fmaxf(o.y, 0.f);
        o.z = fmaxf(o.z, 0.f); o.w = fmaxf(o.w, 0.f);
    }
    st4(out + base, o);
}

// ---------------------------------------------------------------------------
// gemm_qkt: S = adj * (Q @ K^T), in-place on S(=adj). Q/K pre-split hi/lo
// bf16 planes [N,256]. All staging via global_load_lds.
// ---------------------------------------------------------------------------
__global__ __launch_bounds__(256) void gemm_qkt(
    const ushort* __restrict__ Qhi, const ushort* __restrict__ Qlo,
    const ushort* __restrict__ Khi, const ushort* __restrict__ Klo,
    float* __restrict__ S)
{
    __shared__ ushort AhiL[128 * 32];
    __shared__ ushort AloL[128 * 32];
    __shared__ ushort BhiL[128 * 32];
    __shared__ ushort BloL[128 * 32];

    int tid = threadIdx.x, lane = tid & 63, wave = tid >> 6;
    int wi = wave >> 1, wj = wave & 1;
    int lm = lane & 15, lk = lane >> 4;
    int rowBase = blockIdx.y * 128, colBase = blockIdx.x * 128;

    f32x4 acc[4][4] = {};

    for (int k0 = 0; k0 < NH; k0 += 32) {
        #pragma unroll
        for (int p = 0; p < 2; ++p) {
            int ch = wave * 2 + p;
            int rr = ch * 16 + (lane >> 2);
            size_t qoff = ((size_t)(rowBase + rr) * NH + k0) * 2 + (size_t)(lane & 3) * 16;
            size_t koff = ((size_t)(colBase + rr) * NH + k0) * 2 + (size_t)(lane & 3) * 16;
            async_copy16((const char*)Qhi + qoff, (char*)AhiL + ch * 1024);
            async_copy16((const char*)Qlo + qoff, (char*)AloL + ch * 1024);
            async_copy16((const char*)Khi + koff, (char*)BhiL + ch * 1024);
            async_copy16((const char*)Klo + koff, (char*)BloL + ch * 1024);
        }
        __syncthreads();
        bf16x8 af[4], al[4], bh[4], bl[4];
        #pragma unroll
        for (int i = 0; i < 4; ++i) {
            int r = wi * 64 + i * 16 + lm;
            af[i] = *reinterpret_cast<const bf16x8*>(&AhiL[r * 32 + lk * 8]);
            al[i] = *reinterpret_cast<const bf16x8*>(&AloL[r * 32 + lk * 8]);
        }
        #pragma unroll
        for (int j = 0; j < 4; ++j) {
            int n = wj * 64 + j * 16 + lm;
            bh[j] = *reinterpret_cast<const bf16x8*>(&BhiL[n * 32 + lk * 8]);
            bl[j] = *reinterpret_cast<const bf16x8*>(&BloL[n * 32 + lk * 8]);
        }
        #pragma unroll
        for (int i = 0; i < 4; ++i)
            #pragma unroll
            for (int j = 0; j < 4; ++j) {
                acc[i][j] = mfma16(af[i], bh[j], acc[i][j]);
                acc[i][j] = mfma16(af[i], bl[j], acc[i][j]);
                acc[i][j] = mfma16(al[i], bh[j], acc[i][j]);
            }
        __syncthreads();
    }
    #pragma unroll
    for (int i = 0; i < 4; ++i)
        #pragma unroll
        for (int j = 0; j < 4; ++j) {
            int row0 = rowBase + wi * 64 + i * 16 + lk * 4;
            int col = colBase + wj * 64 + j * 16 + lm;
            #pragma unroll
            for (int r = 0; r < 4; ++r) {
                size_t off = (size_t)(row0 + r) * NN + col;
                S[off] = S[off] * acc[i][j][r];
            }
        }
}

// ---------------------------------------------------------------------------
// K6b: in-place row softmax over N columns
// ---------------------------------------------------------------------------
__global__ __launch_bounds__(256) void k6b_softmax(float* __restrict__ S)
{
    int r = blockIdx.x, tid = threadIdx.x;
    float* row = S + (size_t)r * NN;
    float v[24];
    #pragma unroll
    for (int i = 0; i < 24; ++i) v[i] = row[tid + i * 256];
    float m = v[0];
    #pragma unroll
    for (int i = 1; i < 24; ++i) m = fmaxf(m, v[i]);
    #pragma unroll
    for (int o = 32; o > 0; o >>= 1) m = fmaxf(m, __shfl_xor(m, o));
    __shared__ float redm[4];
    __shared__ float reds[4];
    if ((tid & 63) == 0) redm[tid >> 6] = m;
    __syncthreads();
    m = fmaxf(fmaxf(redm[0], redm[1]), fmaxf(redm[2], redm[3]));
    float s = 0.f;
    #pragma unroll
    for (int i = 0; i < 24; ++i) { v[i] = __expf(v[i] - m); s += v[i]; }
    #pragma unroll
    for (int o = 32; o > 0; o >>= 1) s += __shfl_xor(s, o);
    if ((tid & 63) == 0) reds[tid >> 6] = s;
    __syncthreads();
    s = reds[0] + reds[1] + reds[2] + reds[3];
    float inv = 1.f / s;
    #pragma unroll
    for (int i = 0; i < 24; ++i) row[tid + i * 256] = v[i] * inv;
}

// ---------------------------------------------------------------------------
// K6d: Y = Xt @ W2   ([N,256]@[256,8])
// ---------------------------------------------------------------------------
__global__ __launch_bounds__(256) void k6d_Y(
    const float* __restrict__ Xt, const float* __restrict__ W2, float* __restrict__ Y)
{
    int idx = blockIdx.x * 256 + threadIdx.x;
    int r = idx >> 3, j = idx & 7;
    float s = 0.f;
    #pragma unroll 4
    for (int k = 0; k < NH; ++k) s += Xt[(size_t)r * NH + k] * W2[k * 8 + j];
    Y[idx] = s;
}

// ---------------------------------------------------------------------------
// K7: out = softmax(adj @ Y + b2); adj recomputed on the fly
// ---------------------------------------------------------------------------
__global__ __launch_bounds__(256) void k7_out(
    const float* __restrict__ adj0, const float* __restrict__ adj1, const float* __restrict__ adj2,
    const float* __restrict__ nzT, const float* __restrict__ Y,
    const float* __restrict__ b2, float* __restrict__ out)
{
    int r = blockIdx.x, tid = threadIdx.x;
    float acc[8] = {};
    size_t rowOff = (size_t)r * NN;
    for (int c = tid; c < NN; c += 256) {
        float w0 = nzT[c], w1 = nzT[NN + c], w2 = nzT[2 * NN + c];
        float a = w0 * adj0[rowOff + c] + w1 * adj1[rowOff + c] + w2 * adj2[rowOff + c];
        const float* y = Y + (size_t)c * 8;
        float4 y0 = ld4(y), y1 = ld4(y + 4);
        acc[0] += a * y0.x; acc[1] += a * y0.y; acc[2] += a * y0.z; acc[3] += a * y0.w;
        acc[4] += a * y1.x; acc[5] += a * y1.y; acc[6] += a * y1.z; acc[7] += a * y1.w;
    }
    __shared__ float red[256][9];
    #pragma unroll
    for (int j = 0; j < 8; ++j) red[tid][j] = acc[j];
    __syncthreads();
    for (int s2 = 128; s2 > 0; s2 >>= 1) {
        if (tid < s2) {
            #pragma unroll
            for (int j = 0; j < 8; ++j) red[tid][j] += red[tid + s2][j];
        }
        __syncthreads();
    }
    if (tid == 0) {
        float z[8];
        float m = -1e30f;
        #pragma unroll
        for (int j = 0; j < 8; ++j) { z[j] = red[0][j] + b2[j]; m = fmaxf(m, z[j]); }
        float s = 0.f;
        #pragma unroll
        for (int j = 0; j < 8; ++j) { z[j] = __expf(z[j] - m); s += z[j]; }
        float inv = 1.f / s;
        #pragma unroll
        for (int j = 0; j < 8; ++j) out[(size_t)r * NC + j] = z[j] * inv;
    }
}

// ---------------------------------------------------------------------------
extern "C" void kernel_launch(void* const* d_in, const int* in_sizes, int n_in,
                              void* d_out, int out_size, void* d_ws, size_t ws_size,
                              hipStream_t stream)
{
    const float* adj0 = (const float*)d_in[0];
    const float* adj1 = (const float*)d_in[1];
    const float* adj2 = (const float*)d_in[2];
    const float* feat = (const float*)d_in[3];
    const float* Wa1 = (const float*)d_in[4];
    const float* ba1 = (const float*)d_in[5];
    const float* Wa2 = (const float*)d_in[6];
    const float* ba2 = (const float*)d_in[7];
    const float* Wa3 = (const float*)d_in[8];
    const float* ba3 = (const float*)d_in[9];
    const float* Wagg = (const float*)d_in[10];
    const float* bagg = (const float*)d_in[11];
    const float* W1 = (const float*)d_in[12];
    const float* b1 = (const float*)d_in[13];
    const float* Wq = (const float*)d_in[14];
    const float* bq = (const float*)d_in[15];
    const float* Wk = (const float*)d_in[16];
    const float* bk = (const float*)d_in[17];
    const float* Wv = (const float*)d_in[18];
    const float* bv = (const float*)d_in[19];
    const float* W2 = (const float*)d_in[20];
    const float* b2 = (const float*)d_in[21];
    float* out = (float*)d_out;
    float* ws = (float*)d_ws;

    // ---- workspace layout (floats), with lifetime-based reuse ----
    const size_t sz_adj = (size_t)NN * NN;       // 37,748,736
    const size_t sz_m = (size_t)NN * NH;         // 1,572,864
    float* buf_adj = ws;                          // adj -> A_tilde -> attention
    float* nzT     = buf_adj + sz_adj;            // [3][N]
    float* U       = nzT + 3 * NN;                // [3][N][3]
    float* cvec    = U + 9 * NN;                  // [3] (+pad)
    float* fW1     = cvec + 16;                   // [N,256] fp32; later reused: Qhi/Qlo
    float* fW1T_hl = fW1 + sz_m;                  // fW1T hi+lo planes; later: Khi/Klo
    float* xbuf    = fW1T_hl + sz_m;              // x fp32; later reused as Xt
    float* VT_hl   = xbuf + sz_m;                 // V^T hi+lo planes
    float* Rbig    = VT_hl + sz_m;                // 4*sz_m: Cpart(K4) -> Q/K/V -> Cpart(K6c)
    float* Y       = Rbig + 4 * sz_m;             // [N,8]

    ushort* fW1Thi = (ushort*)fW1T_hl;
    ushort* fW1Tlo = fW1Thi + sz_m;
    ushort* VThi = (ushort*)VT_hl;
    ushort* VTlo = VThi + sz_m;
    float* Qm = Rbig;
    float* Km = Rbig + sz_m;
    float* Vm = Rbig + 2 * sz_m;
    ushort* Qhi = (ushort*)fW1;       // fW1 fp32 dead after cvt_t
    ushort* Qlo = Qhi + sz_m;
    ushort* Khi = (ushort*)fW1T_hl;   // fW1T planes dead after K4
    ushort* Klo = Khi + sz_m;
    float* Xt = xbuf;                 // x dead after K5

    float* out_nz = out + (size_t)NN * NC;

    // K0: U, cvec
    k0_prep<<<216, 256, 0, stream>>>(Wa1, Wa2, Wa3, ba1, ba2, ba3, Wagg, bagg, U, cvec);
    // K1: nz
    k1_nz<<<NN / 4, 256, 0, stream>>>(adj0, adj1, adj2, U, cvec, nzT, out_nz);
    // K2: adj
    k2_adj<<<(int)(sz_adj / 4 / 256), 256, 0, stream>>>(adj0, adj1, adj2, nzT, buf_adj);
    // K3: fW1 = feat @ W1 (fp32)
    gemm64<<<dim3(NH / BN, NN / BM), 256, 0, stream>>>(feat, NF, W1, NH, fW1, NH, NF, nullptr, 0);
    // fW1 -> fW1^T hi/lo
    cvt_t<<<dim3(NN / 32, NH / 32), 256, 0, stream>>>(fW1, NN, NH, fW1Thi, fW1Tlo);
    // K4: x = relu(adj @ fW1 + b1)  [MFMA split-bf16, split-K=4]
    gemm_a32_bsplit<<<dim3(2 * 4, NN / GBM), 256, 0, stream>>>(
        buf_adj, NN, fW1Thi, fW1Tlo, NN, Rbig, NH, NN, NN / 4);
    reduce4<<<(int)(sz_m / 4 / 256), 256, 0, stream>>>(Rbig, b1, xbuf, 1);
    // K5: Q, K, V (fp32, K=256)
    gemm64<<<dim3(NH / BN, NN / BM), 256, 0, stream>>>(xbuf, NH, Wq, NH, Qm, NH, NH, bq, 0);
    gemm64<<<dim3(NH / BN, NN / BM), 256, 0, stream>>>(xbuf, NH, Wk, NH, Km, NH, NH, bk, 0);
    gemm64<<<dim3(NH / BN, NN / BM), 256, 0, stream>>>(xbuf, NH, Wv, NH, Vm, NH, NH, bv, 0);
    // splits for attention GEMMs
    cvt_hl<<<(int)(sz_m / 4 / 256), 256, 0, stream>>>(Qm, Qhi, Qlo);
    cvt_hl<<<(int)(sz_m / 4 / 256), 256, 0, stream>>>(Km, Khi, Klo);
    cvt_t<<<dim3(NN / 32, NH / 32), 256, 0, stream>>>(Vm, NN, NH, VThi, VTlo);
    // K6a: S = adj * (Q@K^T) in place [MFMA]
    gemm_qkt<<<dim3(NN / 128, NN / 128), 256, 0, stream>>>(Qhi, Qlo, Khi, Klo, buf_adj);
    // K6b: softmax rows in place
    k6b_softmax<<<NN, 256, 0, stream>>>(buf_adj);
    // K6c: Xt = relu(attention @ V) [MFMA split-bf16, split-K=4]
    gemm_a32_bsplit<<<dim3(2 * 4, NN / GBM), 256, 0, stream>>>(
        buf_adj, NN, VThi, VTlo, NN, Rbig, NH, NN, NN / 4);
    reduce4<<<(int)(sz_m / 4 / 256), 256, 0, stream>>>(Rbig, nullptr, Xt, 1);
    // K6d: Y = Xt @ W2
    k6d_Y<<<NN * NC / 256, 256, 0, stream>>>(Xt, W2, Y);
    // K7: out = softmax(adj @ Y + b2)
    k7_out<<<NN, 256, 0, stream>>>(adj0, adj1, adj2, nzT, Y, b2, out);
}